// Round 8
// baseline (122.034 us; speedup 1.0000x reference)
//
#include <hip/hip_runtime.h>
#include <hip/hip_bf16.h>

typedef __attribute__((ext_vector_type(8))) short bf16x8;
typedef __attribute__((ext_vector_type(4))) float f32x4;

__device__ __forceinline__ ushort f2bf(float x) {
  unsigned u = __float_as_uint(x);
  u = (u + 0x7FFFu + ((u >> 16) & 1u)) >> 16;
  return (ushort)u;
}

// Kt[o][i] = bf16(K[i][o]);  K: [256][1024] f32, Kt: [1024][256] bf16
__global__ void WV_kconv(const float* __restrict__ K, ushort* __restrict__ Kt) {
  int f = (blockIdx.x * 256 + threadIdx.x) * 4;
  int o = f >> 8, i0 = f & 255;
  ushort4 w;
  w.x = f2bf(K[(size_t)(i0 + 0) * 1024 + o]);
  w.y = f2bf(K[(size_t)(i0 + 1) * 1024 + o]);
  w.z = f2bf(K[(size_t)(i0 + 2) * 1024 + o]);
  w.w = f2bf(K[(size_t)(i0 + 3) * 1024 + o]);
  *reinterpret_cast<ushort4*>(Kt + f) = w;
}

// Block (b,h): h = i-half. Stages A_b rows [h*128, h*128+128) -> 64 KB LDS
// (2 blocks/CU, 4 waves/SIMD). 8 waves; wave owns o-strip of 128.
// Bf fragments prefetched one ks ahead to hide L2 latency under MFMA.
// Each half atomicAdds its partial into out (exactly 2 contributors/elem).
__global__ __launch_bounds__(512, 4) void WV_main(
    const float* __restrict__ A, const ushort* __restrict__ Kt,
    float* __restrict__ out) {
  __shared__ short As[128 * 256];  // 64 KB bf16, XOR-swizzled rows
  const int bh = blockIdx.x;
  const int b = bh >> 1, h = bh & 1;
  const float* Ah = A + (size_t)b * 65536 + (size_t)h * 32768;
  const int t = threadIdx.x;

  // ---- stage 128 rows: fp32 -> bf16, swizzle byte ^= (row&7)<<4 ----
  #pragma unroll 2
  for (int it = 0; it < 8; ++it) {
    int c = it * 512 + t;  // chunk of 8 floats
    int m = c >> 5;        // local row 0..127
    int s = c & 31;        // 16B slot within row
    const float4* p = reinterpret_cast<const float4*>(Ah) + c * 2;
    float4 v0 = p[0], v1 = p[1];
    bf16x8 w;
    w[0] = (short)f2bf(v0.x); w[1] = (short)f2bf(v0.y);
    w[2] = (short)f2bf(v0.z); w[3] = (short)f2bf(v0.w);
    w[4] = (short)f2bf(v1.x); w[5] = (short)f2bf(v1.y);
    w[6] = (short)f2bf(v1.z); w[7] = (short)f2bf(v1.w);
    int byteoff = m * 512 + ((s * 16) ^ ((m & 7) << 4));
    *reinterpret_cast<bf16x8*>(reinterpret_cast<char*>(As) + byteoff) = w;
  }
  __syncthreads();

  const int wave = t >> 6, lane = t & 63;
  const int lo = lane & 15;   // row (A) / col (B,D) within tile
  const int hi = lane >> 4;   // 0..3: k-group (A,B) / row-group (D)
  const int wob = wave * 128; // wave's o-strip base

  #pragma unroll 1
  for (int og = 0; og < 2; ++og) {
    float oseg[4] = {0.f, 0.f, 0.f, 0.f};

    #pragma unroll 1
    for (int ig = 0; ig < 2; ++ig) {
      f32x4 acc[4][4];
      #pragma unroll
      for (int a1 = 0; a1 < 4; ++a1)
        #pragma unroll
        for (int a2 = 0; a2 < 4; ++a2)
          acc[a1][a2] = (f32x4){0.f, 0.f, 0.f, 0.f};

      // lane's Kt base: row (wob+og*64+lo), col hi*8; ot adds 16 rows, ks adds 32 cols
      const ushort* KtB = Kt + (size_t)(wob + og * 64 + lo) * 256 + hi * 8;
      bf16x8 Bc[4];
      #pragma unroll
      for (int ot = 0; ot < 4; ++ot)
        Bc[ot] = *reinterpret_cast<const bf16x8*>(KtB + ot * 4096);

      #pragma unroll 1
      for (int ks = 0; ks < 8; ++ks) {
        bf16x8 Bn[4];
        if (ks < 7) {  // prefetch next ks (wave-uniform branch)
          #pragma unroll
          for (int ot = 0; ot < 4; ++ot)
            Bn[ot] = *reinterpret_cast<const bf16x8*>(KtB + ot * 4096 + (ks + 1) * 32);
        }
        const int kk = ks * 32 + hi * 8;
        #pragma unroll
        for (int itl = 0; itl < 4; ++itl) {
          int m = ig * 64 + itl * 16 + lo;
          int byteoff = m * 512 + ((kk * 2) ^ ((m & 7) << 4));
          bf16x8 Af = *reinterpret_cast<const bf16x8*>(
              reinterpret_cast<char*>(As) + byteoff);
          #pragma unroll
          for (int ot = 0; ot < 4; ++ot)
            acc[itl][ot] = __builtin_amdgcn_mfma_f32_16x16x32_bf16(
                Af, Bc[ot], acc[itl][ot], 0, 0, 0);
        }
        if (ks < 7) {
          #pragma unroll
          for (int ot = 0; ot < 4; ++ot) Bc[ot] = Bn[ot];
        }
      }

      // epilogue: oseg[ot] += sum over this ig's 64 i-rows (global i = h*128+...)
      #pragma unroll
      for (int itl = 0; itl < 4; ++itl) {
        const int i0 = h * 128 + ig * 64 + itl * 16 + hi * 4;
        #pragma unroll
        for (int ot = 0; ot < 4; ++ot) {
          int n = wob + og * 64 + ot * 16 + lo;
          ushort4 wv = *reinterpret_cast<const ushort4*>(Kt + (size_t)n * 256 + i0);
          f32x4 a = acc[itl][ot];
          float s = __uint_as_float((unsigned)wv.x << 16) * a[0]
                  + __uint_as_float((unsigned)wv.y << 16) * a[1]
                  + __uint_as_float((unsigned)wv.z << 16) * a[2]
                  + __uint_as_float((unsigned)wv.w << 16) * a[3];
          s += __shfl_xor(s, 16);
          s += __shfl_xor(s, 32);
          oseg[ot] += s;
        }
      }
    }

    if (lane < 16) {
      #pragma unroll
      for (int ot = 0; ot < 4; ++ot)
        atomicAdd(&out[(size_t)b * 1024 + wob + og * 64 + ot * 16 + lane],
                  oseg[ot]);
    }
  }
}

extern "C" void kernel_launch(void* const* d_in, const int* in_sizes, int n_in,
                              void* d_out, int out_size, void* d_ws, size_t ws_size,
                              hipStream_t stream) {
  const float* A = (const float*)d_in[0];   // (256,256,256) f32
  const float* K = (const float*)d_in[1];   // (256,1024)   f32
  float* out = (float*)d_out;               // (256,1024)   f32
  ushort* Kt = (ushort*)d_ws;               // (1024,256)   bf16
  hipMemsetAsync(d_out, 0, (size_t)out_size * sizeof(float), stream);
  WV_kconv<<<256, 256, 0, stream>>>(K, Kt);
  WV_main<<<512, 512, 0, stream>>>(A, Kt, out);
}

// Round 9
// 106.131 us; speedup vs baseline: 1.1498x; 1.1498x over previous
//
#include <hip/hip_runtime.h>
#include <hip/hip_bf16.h>

typedef __attribute__((ext_vector_type(8))) short bf16x8;
typedef __attribute__((ext_vector_type(4))) float f32x4;

__device__ __forceinline__ ushort f2bf(float x) {
  unsigned u = __float_as_uint(x);
  u = (u + 0x7FFFu + ((u >> 16) & 1u)) >> 16;
  return (ushort)u;
}

// Kt[o][i] = bf16(K[i][o]);  K: [256][1024] f32, Kt: [1024][256] bf16
__global__ void WV_kconv(const float* __restrict__ K, ushort* __restrict__ Kt) {
  int f = (blockIdx.x * 256 + threadIdx.x) * 4;
  int o = f >> 8, i0 = f & 255;
  ushort4 w;
  w.x = f2bf(K[(size_t)(i0 + 0) * 1024 + o]);
  w.y = f2bf(K[(size_t)(i0 + 1) * 1024 + o]);
  w.z = f2bf(K[(size_t)(i0 + 2) * 1024 + o]);
  w.w = f2bf(K[(size_t)(i0 + 3) * 1024 + o]);
  *reinterpret_cast<ushort4*>(Kt + f) = w;
}

// Block (b,h): h = i-half. Stages A_b rows [h*128, h*128+128) -> 64 KB LDS
// (2 blocks/CU, 4 waves/SIMD). 8 waves; wave owns o-strip of 128.
// NOTE on __launch_bounds__: on this hipcc the 2nd arg acts as CUDA-style
// min-BLOCKS-per-CU: (512,2) -> 128-VGPR cap (fits ~115 demand, no spill);
// (512,4) -> 64-VGPR cap (spilled acc, 68 MB scratch writes, round 8).
__global__ __launch_bounds__(512, 2) void WV_main(
    const float* __restrict__ A, const ushort* __restrict__ Kt,
    float* __restrict__ out) {
  __shared__ short As[128 * 256];  // 64 KB bf16, XOR-swizzled rows
  const int bh = blockIdx.x;
  const int b = bh >> 1, h = bh & 1;
  const float* Ah = A + (size_t)b * 65536 + (size_t)h * 32768;
  const int t = threadIdx.x;

  // ---- stage 128 rows: fp32 -> bf16, swizzle byte ^= (row&7)<<4 ----
  #pragma unroll 2
  for (int it = 0; it < 8; ++it) {
    int c = it * 512 + t;  // chunk of 8 floats
    int m = c >> 5;        // local row 0..127
    int s = c & 31;        // 16B slot within row
    const float4* p = reinterpret_cast<const float4*>(Ah) + c * 2;
    float4 v0 = p[0], v1 = p[1];
    bf16x8 w;
    w[0] = (short)f2bf(v0.x); w[1] = (short)f2bf(v0.y);
    w[2] = (short)f2bf(v0.z); w[3] = (short)f2bf(v0.w);
    w[4] = (short)f2bf(v1.x); w[5] = (short)f2bf(v1.y);
    w[6] = (short)f2bf(v1.z); w[7] = (short)f2bf(v1.w);
    int byteoff = m * 512 + ((s * 16) ^ ((m & 7) << 4));
    *reinterpret_cast<bf16x8*>(reinterpret_cast<char*>(As) + byteoff) = w;
  }
  __syncthreads();

  const int wave = t >> 6, lane = t & 63;
  const int lo = lane & 15;   // row (A) / col (B,D) within tile
  const int hi = lane >> 4;   // 0..3: k-group (A,B) / row-group (D)
  const int wob = wave * 128; // wave's o-strip base

  #pragma unroll 1
  for (int og = 0; og < 2; ++og) {
    float oseg[4] = {0.f, 0.f, 0.f, 0.f};

    #pragma unroll 1
    for (int ig = 0; ig < 2; ++ig) {
      f32x4 acc[4][4];
      #pragma unroll
      for (int a1 = 0; a1 < 4; ++a1)
        #pragma unroll
        for (int a2 = 0; a2 < 4; ++a2)
          acc[a1][a2] = (f32x4){0.f, 0.f, 0.f, 0.f};

      // lane's Kt base: row (wob+og*64+lo), col hi*8; ot adds 16 rows, ks adds 32 cols
      const ushort* KtB = Kt + (size_t)(wob + og * 64 + lo) * 256 + hi * 8;
      bf16x8 Bc[4];
      #pragma unroll
      for (int ot = 0; ot < 4; ++ot)
        Bc[ot] = *reinterpret_cast<const bf16x8*>(KtB + ot * 4096);

      #pragma unroll 1
      for (int ks = 0; ks < 8; ++ks) {
        bf16x8 Bn[4];
        if (ks < 7) {  // prefetch next ks (wave-uniform branch)
          #pragma unroll
          for (int ot = 0; ot < 4; ++ot)
            Bn[ot] = *reinterpret_cast<const bf16x8*>(KtB + ot * 4096 + (ks + 1) * 32);
        }
        const int kk = ks * 32 + hi * 8;
        #pragma unroll
        for (int itl = 0; itl < 4; ++itl) {
          int m = ig * 64 + itl * 16 + lo;
          int byteoff = m * 512 + ((kk * 2) ^ ((m & 7) << 4));
          bf16x8 Af = *reinterpret_cast<const bf16x8*>(
              reinterpret_cast<char*>(As) + byteoff);
          #pragma unroll
          for (int ot = 0; ot < 4; ++ot)
            acc[itl][ot] = __builtin_amdgcn_mfma_f32_16x16x32_bf16(
                Af, Bc[ot], acc[itl][ot], 0, 0, 0);
        }
        if (ks < 7) {
          #pragma unroll
          for (int ot = 0; ot < 4; ++ot) Bc[ot] = Bn[ot];
        }
      }

      // epilogue: oseg[ot] += sum over this ig's 64 i-rows (global i = h*128+...)
      #pragma unroll
      for (int itl = 0; itl < 4; ++itl) {
        const int i0 = h * 128 + ig * 64 + itl * 16 + hi * 4;
        #pragma unroll
        for (int ot = 0; ot < 4; ++ot) {
          int n = wob + og * 64 + ot * 16 + lo;
          ushort4 wv = *reinterpret_cast<const ushort4*>(Kt + (size_t)n * 256 + i0);
          f32x4 a = acc[itl][ot];
          float s = __uint_as_float((unsigned)wv.x << 16) * a[0]
                  + __uint_as_float((unsigned)wv.y << 16) * a[1]
                  + __uint_as_float((unsigned)wv.z << 16) * a[2]
                  + __uint_as_float((unsigned)wv.w << 16) * a[3];
          s += __shfl_xor(s, 16);
          s += __shfl_xor(s, 32);
          oseg[ot] += s;
        }
      }
    }

    if (lane < 16) {
      #pragma unroll
      for (int ot = 0; ot < 4; ++ot)
        atomicAdd(&out[(size_t)b * 1024 + wob + og * 64 + ot * 16 + lane],
                  oseg[ot]);
    }
  }
}

extern "C" void kernel_launch(void* const* d_in, const int* in_sizes, int n_in,
                              void* d_out, int out_size, void* d_ws, size_t ws_size,
                              hipStream_t stream) {
  const float* A = (const float*)d_in[0];   // (256,256,256) f32
  const float* K = (const float*)d_in[1];   // (256,1024)   f32
  float* out = (float*)d_out;               // (256,1024)   f32
  ushort* Kt = (ushort*)d_ws;               // (1024,256)   bf16
  hipMemsetAsync(d_out, 0, (size_t)out_size * sizeof(float), stream);
  WV_kconv<<<256, 256, 0, stream>>>(K, Kt);
  WV_main<<<512, 512, 0, stream>>>(A, Kt, out);
}